// Round 3
// baseline (289.420 us; speedup 1.0000x reference)
//
#include <hip/hip_runtime.h>

// DerivativeRBF: X(512,16), X2(512,16), uls(16), uvar(1) ->
//   K(512,512) | grad_K(8192,512) | hess_K(8192,8192), concatenated in d_out.
// 286 MB f32 output vs 64 KB input: pure write-bandwidth problem.

#define NN 512
#define DD 16
#define NDD 8192
#define GOFF (NN * NN)                 // grad_K offset: 262144
#define HOFF (NN * NN + NDD * NN)      // hess_K offset: 4456448

// native clang vector type: __builtin_nontemporal_store rejects HIP_vector_type
typedef float fv4 __attribute__((ext_vector_type(4)));

__device__ __forceinline__ float softplus_f(float x) {
    // stable softplus, matches jax.nn.softplus
    return fmaxf(x, 0.0f) + log1pf(expf(-fabsf(x)));
}

__device__ __forceinline__ void nt_store4(float* p, float a, float b, float c, float d) {
    fv4 v = {a, b, c, d};
    __builtin_nontemporal_store(v, (fv4*)p);
}

// Compute s[r][d] = (Xi[d] - Y[r][d]) / l_d^2 and k[r] = var*exp(-0.25*sqdist)
// for 4 consecutive Y rows. All loops unrolled: register arrays stay registers.
__device__ __forceinline__ void compute_sk(const float* __restrict__ Xi,
                                           const float* __restrict__ Y0,
                                           const float* __restrict__ s_il2,
                                           float var,
                                           float (&s)[4][DD], float (&k)[4])
{
    float xi[DD];
    const fv4* Xi4 = (const fv4*)Xi;
    #pragma unroll
    for (int c = 0; c < 4; ++c) {
        fv4 v = Xi4[c];
        xi[c * 4 + 0] = v.x; xi[c * 4 + 1] = v.y;
        xi[c * 4 + 2] = v.z; xi[c * 4 + 3] = v.w;
    }
    #pragma unroll
    for (int r = 0; r < 4; ++r) {
        const fv4* Y4 = (const fv4*)(Y0 + r * DD);
        float sq = 0.f;
        #pragma unroll
        for (int c = 0; c < 4; ++c) {
            fv4 v = Y4[c];
            float dif;
            dif = xi[c*4+0] - v.x; s[r][c*4+0] = dif * s_il2[c*4+0]; sq += s[r][c*4+0] * dif;
            dif = xi[c*4+1] - v.y; s[r][c*4+1] = dif * s_il2[c*4+1]; sq += s[r][c*4+1] * dif;
            dif = xi[c*4+2] - v.z; s[r][c*4+2] = dif * s_il2[c*4+2]; sq += s[r][c*4+2] * dif;
            dif = xi[c*4+3] - v.w; s[r][c*4+3] = dif * s_il2[c*4+3]; sq += s[r][c*4+3] * dif;
        }
        k[r] = var * expf(-0.25f * sq);
    }
}

// Write 8 'a' rows (A0..A0+7) of the 16x16 hess block for 4 consecutive j.
// A0 is a template arg so every register-array index is compile-time.
template<int A0>
__device__ __forceinline__ void hess_store(const float (&s)[4][DD], const float (&k)[4],
                                           const float* __restrict__ s_h2,
                                           float* __restrict__ base)
{
    #pragma unroll
    for (int aa = 0; aa < 8; ++aa) {
        const int a = A0 + aa;
        float h2a = s_h2[a];
        float ta0 = -0.25f * k[0] * s[0][a];
        float ta1 = -0.25f * k[1] * s[1][a];
        float ta2 = -0.25f * k[2] * s[2][a];
        float ta3 = -0.25f * k[3] * s[3][a];
        float* row = base + (size_t)a * ((size_t)NN * NDD);
        #pragma unroll
        for (int b = 0; b < DD; ++b) {
            float v0 = ta0 * s[0][b];
            float v1 = ta1 * s[1][b];
            float v2 = ta2 * s[2][b];
            float v3 = ta3 * s[3][b];
            if (b == a) {   // compile-time after unroll
                v0 = fmaf(k[0], h2a, v0); v1 = fmaf(k[1], h2a, v1);
                v2 = fmaf(k[2], h2a, v2); v3 = fmaf(k[3], h2a, v3);
            }
            nt_store4(row + (size_t)b * NN, v0, v1, v2, v3);
        }
    }
}

__global__ __launch_bounds__(256) void drbf_kernel(
    const float* __restrict__ X, const float* __restrict__ X2,
    const float* __restrict__ uls, const float* __restrict__ uvar,
    float* __restrict__ out)
{
    __shared__ float s_il2[DD];   // 1/l^2
    __shared__ float s_h2[DD];    // 0.5/l^2
    __shared__ float s_var;
    const int t = threadIdx.x;
    if (t < DD) {
        float ls = softplus_f(uls[t]);
        float il2 = 1.0f / (ls * ls);
        s_il2[t] = il2;
        s_h2[t] = 0.5f * il2;
    }
    if (t == DD) s_var = softplus_f(uvar[0]);
    __syncthreads();
    const float var = s_var;
    const int bx = blockIdx.x;

    if (bx < 512) {
        // hess_K. Blocks 0..255 -> a=0..7, blocks 256..511 -> a=8..15.
        // Thread owns (i, j..j+3): lanes hold consecutive j-quads -> each
        // wave store instruction covers 1 KB contiguous.
        const int ah = bx >> 8;
        const int h  = (bx & 255) * 256 + t;
        const int j  = (h & 127) * 4;
        const int i  = h >> 7;

        float s[4][DD], k[4];
        compute_sk(X + i * DD, X + j * DD, s_il2, var, s, k);

        float* base = out + HOFF + (size_t)i * NDD + j;
        if (ah == 0) hess_store<0>(s, k, s_h2, base);
        else         hess_store<8>(s, k, s_h2, base);
    } else {
        // K + grad_K. Thread owns (n, m..m+3).
        const int g = (bx - 512) * 256 + t;
        const int m = (g & 127) * 4;
        const int n = g >> 7;

        float s[4][DD], k[4];
        compute_sk(X + n * DD, X2 + m * DD, s_il2, var, s, k);

        nt_store4(out + (size_t)n * NN + m, k[0], k[1], k[2], k[3]);

        #pragma unroll
        for (int d = 0; d < DD; ++d) {
            nt_store4(out + GOFF + (size_t)(d * NN + n) * NN + m,
                      -0.5f * s[0][d] * k[0], -0.5f * s[1][d] * k[1],
                      -0.5f * s[2][d] * k[2], -0.5f * s[3][d] * k[3]);
        }
    }
}

extern "C" void kernel_launch(void* const* d_in, const int* in_sizes, int n_in,
                              void* d_out, int out_size, void* d_ws, size_t ws_size,
                              hipStream_t stream) {
    const float* X    = (const float*)d_in[0];
    const float* X2   = (const float*)d_in[1];
    const float* uls  = (const float*)d_in[2];
    const float* uvar = (const float*)d_in[3];
    float* out = (float*)d_out;
    // 512 hess blocks + 256 K/grad blocks = 768 blocks (3 per CU).
    drbf_kernel<<<dim3(768), dim3(256), 0, stream>>>(X, X2, uls, uvar, out);
}